// Round 3
// baseline (2270.586 us; speedup 1.0000x reference)
//
#include <hip/hip_runtime.h>

// Problem constants
#define B_ 8
#define C_ 128
#define HW_ 512
#define PS 16
#define E_ 16
#define NP 1024   // patches per batch (32x32)
#define FD 512

// d_out layout (flat f32):
// [0, 131072)        gates   [B, NP, E]
// [131072, 163840)   top_k_indices as float [B, NP, 4]
// [163840, 196608)   top_k_values [B, NP, 4]
// [196608]           aux_loss (0.0f)

// freq[b,e] = sum_d femb[b,d]*fw[e,d], computed accurately (f64) and rounded
// to f32 once ("central" estimate of any reasonable f32 BLAS evaluation).
__global__ void freq_kernel(const float* __restrict__ femb,
                            const float* __restrict__ fw,
                            float* __restrict__ freqf,
                            float* __restrict__ out) {
    int t = threadIdx.x;
    if (t == 0) out[196608] = 0.0f;  // aux_loss, rewritten every launch
    if (t < 128) {
        int b = t >> 4, e = t & 15;
        const float* fe = femb + b * FD;
        const float* w  = fw + e * FD;
        double s = 0.0;
        for (int i = 0; i < FD; ++i)
            s = fma((double)fe[i], (double)w[i], s);
        freqf[t] = (float)s;
    }
}

// Faithful-f32 replication of the numpy reference.
// Grid: 512 blocks = b(8) x patch-group(64). Block: 256 threads = 16 patches x 16 experts.
// Each thread computes ONE (patch, expert) logit as a strictly sequential f32
// sum over (c, p, q) with separate round-to-nearest mul and add (no FMA), the
// np.einsum(optimize=False) accumulation semantics.
__global__ __launch_bounds__(256) void patch_route_kernel(
    const float* __restrict__ x,
    const float* __restrict__ noise,
    const float* __restrict__ conv_w,
    const float* __restrict__ conv_b,
    const float* __restrict__ freqf,
    float* __restrict__ out) {

  const int blk = blockIdx.x;     // 0..511
  const int b   = blk >> 6;
  const int pg  = blk & 63;       // patch group of 16
  const int t   = threadIdx.x;
  const int lp  = t >> 4;         // local patch 0..15
  const int e   = t & 15;         // expert
  const int patch = pg * 16 + lp;        // 0..1023
  const int pi = patch >> 5, pj = patch & 31;

  const float* xb = x + (size_t)b * (C_ * HW_ * HW_)
                      + (size_t)(pi * PS) * HW_ + pj * PS;
  const float* wb = conv_w + (size_t)e * 32768;

  float acc = 0.0f;
  for (int c = 0; c < 128; ++c) {
    const float* xc = xb + (size_t)c * (HW_ * HW_);
    const float* wc = wb + c * 256;
    #pragma unroll
    for (int p = 0; p < 16; ++p) {
      float4 xq[4], wq[4];
      const float4* xr = reinterpret_cast<const float4*>(xc + p * HW_);
      const float4* wr = reinterpret_cast<const float4*>(wc + p * 16);
      #pragma unroll
      for (int q = 0; q < 4; ++q) { xq[q] = xr[q]; wq[q] = wr[q]; }
      const float* xs = reinterpret_cast<const float*>(xq);
      const float* ws = reinterpret_cast<const float*>(wq);
      #pragma unroll
      for (int q = 0; q < 16; ++q)
        acc = __fadd_rn(acc, __fmul_rn(xs[q], ws[q]));   // strict seq f32, no FMA
    }
  }

  // logits, f32 adds in reference order: (+conv_b) -> (+freq) -> (+noise)
  float lg = __fadd_rn(acc, conv_b[e]);
  lg = __fadd_rn(lg, freqf[b * 16 + e]);
  lg = __fadd_rn(lg, noise[((size_t)b * NP + patch) * 16 + e]);

  __shared__ float slg[16][16];
  slg[lp][e] = lg;
  __syncthreads();

  // ---- f32 softmax + top-4, one thread per patch ----
  if (t < 16) {
    const int pp = t;
    const int pat = pg * 16 + pp;
    float v[16];
    #pragma unroll
    for (int i = 0; i < 16; ++i) v[i] = slg[pp][i];

    float m = v[0];
    #pragma unroll
    for (int i = 1; i < 16; ++i) m = fmaxf(m, v[i]);

    float ex[16];
    #pragma unroll
    for (int i = 0; i < 16; ++i) ex[i] = expf(v[i] - m);

    // numpy pairwise-16 sum for the denominator
    float r[8];
    #pragma unroll
    for (int j = 0; j < 8; ++j) r[j] = __fadd_rn(ex[j], ex[j + 8]);
    float d0 = __fadd_rn(__fadd_rn(r[0], r[1]), __fadd_rn(r[2], r[3]));
    float d1 = __fadd_rn(__fadd_rn(r[4], r[5]), __fadd_rn(r[6], r[7]));
    float den = __fadd_rn(d0, d1);

    float s[16];
    #pragma unroll
    for (int i = 0; i < 16; ++i) s[i] = ex[i] / den;   // IEEE f32 div

    // top-4 on f32 scores, strict >, lowest index first on ties (lax.top_k)
    unsigned mask = 0;
    int bidx[4]; float bval[4];
    #pragma unroll
    for (int j = 0; j < 4; ++j) {
      int bi = 0; float bv = -1.0f;
      #pragma unroll
      for (int i = 0; i < 16; ++i) {
        if (!((mask >> i) & 1u) && s[i] > bv) { bv = s[i]; bi = i; }
      }
      mask |= 1u << bi;
      bidx[j] = bi; bval[j] = bv;
    }

    const size_t po = (size_t)b * NP + pat;
    float* gout = out + po * 16;
    float* iout = out + 131072 + po * 4;
    float* vout = out + 163840 + po * 4;
    #pragma unroll
    for (int j = 0; j < 4; ++j) {
      iout[j] = (float)bidx[j];
      vout[j] = bval[j];
    }
    #pragma unroll
    for (int i = 0; i < 16; ++i)
      gout[i] = ((mask >> i) & 1u) ? s[i] : 0.0f;
  }
}

extern "C" void kernel_launch(void* const* d_in, const int* in_sizes, int n_in,
                              void* d_out, int out_size, void* d_ws, size_t ws_size,
                              hipStream_t stream) {
  const float* x     = (const float*)d_in[0];
  const float* femb  = (const float*)d_in[1];
  const float* noise = (const float*)d_in[2];
  const float* cw    = (const float*)d_in[3];
  const float* cb    = (const float*)d_in[4];
  const float* fw    = (const float*)d_in[5];
  float* out = (float*)d_out;
  float* freqf = (float*)d_ws;   // 128 floats

  hipLaunchKernelGGL(freq_kernel, dim3(1), dim3(128), 0, stream,
                     femb, fw, freqf, out);
  hipLaunchKernelGGL(patch_route_kernel, dim3(512), dim3(256), 0, stream,
                     x, noise, cw, cb, freqf, out);
}